// Round 12
// baseline (439.432 us; speedup 1.0000x reference)
//
#include <hip/hip_runtime.h>

#define CC    64
#define HH    3
#define ECC   32
#define HCdim 192
#define NEG_SLOPE 0.2f
#define ASHIFT 12.0f        // global softmax shift (shift-invariant)
#define LOG2E  1.44269504f

typedef float v2f __attribute__((ext_vector_type(2)));

// K0: u[h*32+k] = sum_c We[k*192 + h*64 + c] * wt[h*192 + 64 + c]
__global__ void tm_k0(const float* __restrict__ We, const float* __restrict__ wt,
                      float* __restrict__ u) {
    int t = threadIdx.x;
    if (t >= HH * ECC) return;
    int h = t >> 5, k = t & 31;
    float s = 0.f;
    #pragma unroll
    for (int c = 0; c < CC; ++c)
        s = fmaf(We[k * HCdim + h * CC + c], wt[h * HCdim + CC + c], s);
    u[t] = s;
}

// K1: xp(f16) = x @ Wn (N x 64 @ 64 x 192), 4-row register blocking,
// fused per-node scalars sA (f32) and deg histogram.
#define K1_ROWS 64
__global__ __launch_bounds__(192) void tm_k1(const float* __restrict__ x,
        const float* __restrict__ Wn, const float* __restrict__ wt,
        const int* __restrict__ ei, int* __restrict__ deg,
        _Float16* __restrict__ xp16, float* __restrict__ sA, int N, int E) {
    __shared__ float wl[CC * HCdim];     // 48 KiB [k][t]
    __shared__ float xl[K1_ROWS * CC];   // 16 KiB [r][k]
    const int t = threadIdx.x;
    // fused deg histogram over dst (overlaps GEMM; atomics retire async)
    for (int i = blockIdx.x * 192 + t; i < E; i += gridDim.x * 192)
        atomicAdd(&deg[ei[E + i]], 1);
    const int h = t >> 6, c = t & 63;
    {
        float4* wl4 = (float4*)wl;
        const float4* Wn4 = (const float4*)Wn;
        for (int i = t; i < CC * HCdim / 4; i += 192) wl4[i] = Wn4[i];
    }
    const int base = blockIdx.x * K1_ROWS;
    const int rows = min(K1_ROWS, N - base);
    {
        float4* xl4 = (float4*)xl;
        const float4* x4 = (const float4*)(x + (size_t)base * CC);
        for (int i = t; i < rows * CC / 4; i += 192) xl4[i] = x4[i];
    }
    const float w0c = wt[h * HCdim + c];
    const float w2c = wt[h * HCdim + 2 * CC + c];
    __syncthreads();
    for (int rt = 0; rt < rows; rt += 4) {
        float acc0 = 0.f, acc1 = 0.f, acc2 = 0.f, acc3 = 0.f;
        #pragma unroll 4
        for (int k = 0; k < CC; k += 4) {
            const float w0  = wl[(k + 0) * HCdim + t];
            const float w1  = wl[(k + 1) * HCdim + t];
            const float w2_ = wl[(k + 2) * HCdim + t];
            const float w3  = wl[(k + 3) * HCdim + t];
            const float4 xa = *(const float4*)&xl[(rt + 0) * CC + k];
            const float4 xb = *(const float4*)&xl[(rt + 1) * CC + k];
            const float4 xc = *(const float4*)&xl[(rt + 2) * CC + k];
            const float4 xd = *(const float4*)&xl[(rt + 3) * CC + k];
            acc0 = fmaf(xa.x, w0, fmaf(xa.y, w1, fmaf(xa.z, w2_, fmaf(xa.w, w3, acc0))));
            acc1 = fmaf(xb.x, w0, fmaf(xb.y, w1, fmaf(xb.z, w2_, fmaf(xb.w, w3, acc1))));
            acc2 = fmaf(xc.x, w0, fmaf(xc.y, w1, fmaf(xc.z, w2_, fmaf(xc.w, w3, acc2))));
            acc3 = fmaf(xd.x, w0, fmaf(xd.y, w1, fmaf(xd.z, w2_, fmaf(xd.w, w3, acc3))));
        }
        #pragma unroll
        for (int r = 0; r < 4; ++r) {
            const float v = (r == 0) ? acc0 : (r == 1) ? acc1 : (r == 2) ? acc2 : acc3;
            const int n = base + rt + r;
            xp16[(size_t)n * HCdim + t] = (_Float16)v;
            float a0 = v * w0c, a2 = v * w2c;
            #pragma unroll
            for (int o = 32; o; o >>= 1) {
                a0 += __shfl_xor(a0, o);
                a2 += __shfl_xor(a2, o);
            }
            if (c == 0) {
                sA[n * 8 + h]     = a0;
                sA[n * 8 + 4 + h] = a2;
            }
        }
    }
}

// scanA: per-block (256) sums of deg
__global__ __launch_bounds__(256) void tm_scanA(const int* __restrict__ deg,
        int* __restrict__ bsum, int N) {
    __shared__ int sd[256];
    int t = threadIdx.x, n = blockIdx.x * 256 + t;
    sd[t] = (n < N) ? deg[n] : 0;
    __syncthreads();
    for (int o = 128; o; o >>= 1) {
        if (t < o) sd[t] += sd[t + o];
        __syncthreads();
    }
    if (!t) bsum[blockIdx.x] = sd[0];
}

// scanB: exclusive scan of block sums (nb <= 256), single block
__global__ __launch_bounds__(256) void tm_scanB(const int* __restrict__ bsum,
        int* __restrict__ boff, int nb) {
    __shared__ int sd[256];
    int t = threadIdx.x;
    int v = (t < nb) ? bsum[t] : 0;
    sd[t] = v;
    __syncthreads();
    for (int o = 1; o < 256; o <<= 1) {
        int x = (t >= o) ? sd[t - o] : 0;
        __syncthreads();
        sd[t] += x;
        __syncthreads();
    }
    if (t < nb) boff[t] = sd[t] - v;   // exclusive
}

// scanC: per-element exclusive offsets; off[N]=E; cursor=off copy
__global__ __launch_bounds__(256) void tm_scanC(const int* __restrict__ deg,
        const int* __restrict__ boff, int* __restrict__ off,
        int* __restrict__ cursor, int N) {
    __shared__ int sd[256];
    int t = threadIdx.x, n = blockIdx.x * 256 + t;
    int v = (n < N) ? deg[n] : 0;
    sd[t] = v;
    __syncthreads();
    for (int o = 1; o < 256; o <<= 1) {
        int x = (t >= o) ? sd[t - o] : 0;
        __syncthreads();
        sd[t] += x;
        __syncthreads();
    }
    if (n < N) {
        int ex = boff[blockIdx.x] + sd[t] - v;
        off[n] = ex;
        cursor[n] = ex;
        if (n == N - 1) off[N] = ex + v;
    }
}

// K_alpha (+fused scatter): edge-order. alphaE holds (leaky(a)-ASHIFT)*log2e
// so agg's weight is a single v_exp. perm = {src f16-row byte off, e ea byte off}.
__global__ __launch_bounds__(256) void tm_alpha(const int* __restrict__ ei,
        const float* __restrict__ ea, const float* __restrict__ u,
        const float* __restrict__ sA, int* __restrict__ cursor,
        float4* __restrict__ alphaE, int2* __restrict__ perm, int E) {
    __shared__ float ul[HH * ECC];
    const int t = threadIdx.x;
    if (t < HH * ECC) ul[t] = u[t];
    __syncthreads();
    const int e = blockIdx.x * 256 + t;
    if (e >= E) return;
    const int src = ei[e];
    const int dst = ei[E + e];
    float av[ECC];
    const float4* p4 = (const float4*)(ea + (size_t)e * ECC);
    #pragma unroll
    for (int q = 0; q < 8; ++q) {
        float4 v = p4[q];
        av[4*q] = v.x; av[4*q+1] = v.y; av[4*q+2] = v.z; av[4*q+3] = v.w;
    }
    float d0 = 0.f, d1 = 0.f, d2 = 0.f;
    #pragma unroll
    for (int k = 0; k < ECC; ++k) {
        d0 = fmaf(av[k], ul[k], d0);
        d1 = fmaf(av[k], ul[ECC + k], d1);
        d2 = fmaf(av[k], ul[2 * ECC + k], d2);
    }
    const float4 s0 = *(const float4*)(sA + (size_t)dst * 8);
    const float4 s2 = *(const float4*)(sA + (size_t)src * 8 + 4);
    float a0 = s0.x + d0 + s2.x;
    float a1 = s0.y + d1 + s2.y;
    float a2 = s0.z + d2 + s2.z;
    a0 = (a0 >= 0.f) ? a0 : NEG_SLOPE * a0;
    a1 = (a1 >= 0.f) ? a1 : NEG_SLOPE * a1;
    a2 = (a2 >= 0.f) ? a2 : NEG_SLOPE * a2;
    alphaE[e] = make_float4((a0 - ASHIFT) * LOG2E,
                            (a1 - ASHIFT) * LOG2E,
                            (a2 - ASHIFT) * LOG2E, 0.f);
    const int pos = atomicAdd(&cursor[dst], 1);
    perm[pos] = make_int2(src * (HCdim * 2), e * (ECC * 4));
}

// K_agg: ONE WAVE per node handles all 3 heads. ea row / perm / alpha loaded
// once per edge (was 3x across head-waves); 3 independent dot chains give
// in-wave ILP. 4 independent waves per 256-block, grid-strided ~8 nodes/wave.
__global__ __launch_bounds__(256) void tm_agg(const int2* __restrict__ perm,
        const int* __restrict__ off, const float* __restrict__ ea,
        const float* __restrict__ We, const float* __restrict__ alphaE,
        const _Float16* __restrict__ xp16, float* __restrict__ aggrN, int N) {
    const int t = threadIdx.x;
    const int wv = t >> 6, lane = t & 63;
    const char* __restrict__ ea_b = (const char*)ea;
    const char* __restrict__ xp_b = (const char*)xp16;
    const char* __restrict__ al_b = (const char*)alphaE;
    v2f wcol2[HH][16];   // 96 VGPR: We columns for all 3 heads
    #pragma unroll
    for (int h = 0; h < HH; ++h)
        #pragma unroll
        for (int k2 = 0; k2 < 16; ++k2) {
            wcol2[h][k2].x = We[(2 * k2)     * HCdim + h * CC + lane];
            wcol2[h][k2].y = We[(2 * k2 + 1) * HCdim + h * CC + lane];
        }
    for (int n = blockIdx.x * 4 + wv; n < N; n += gridDim.x * 4) {
        const int start = off[n], end = off[n + 1];
        float s0 = 0.f, s1 = 0.f, s2 = 0.f;
        float ac0 = 0.f, ac1 = 0.f, ac2 = 0.f;
        int2 pe = (start < end) ? perm[start] : make_int2(0, 0);
        for (int pos = start; pos < end; ++pos) {
            const int2 cur = pe;
            if (pos + 1 < end) pe = perm[pos + 1];
            const int so = __builtin_amdgcn_readfirstlane(cur.x);
            const int eo = __builtin_amdgcn_readfirstlane(cur.y);
            const float4 av = *(const float4*)(al_b + (eo >> 3));
            const float4* q4 = (const float4*)(ea_b + eo);
            const _Float16* xr = (const _Float16*)(xp_b + so) + lane;
            const float xj0 = (float)xr[0];
            const float xj1 = (float)xr[CC];
            const float xj2 = (float)xr[2 * CC];
            v2f d0 = {0.f, 0.f}, d1 = {0.f, 0.f}, d2 = {0.f, 0.f};
            #pragma unroll
            for (int q = 0; q < 8; ++q) {
                const float4 v = q4[q];
                const v2f lo = {v.x, v.y}, hi = {v.z, v.w};
                d0 = lo * wcol2[0][2 * q]     + d0;
                d0 = hi * wcol2[0][2 * q + 1] + d0;
                d1 = lo * wcol2[1][2 * q]     + d1;
                d1 = hi * wcol2[1][2 * q + 1] + d1;
                d2 = lo * wcol2[2][2 * q]     + d2;
                d2 = hi * wcol2[2][2 * q + 1] + d2;
            }
            const float p0 = exp2f(av.x);
            const float p1 = exp2f(av.y);
            const float p2 = exp2f(av.z);
            s0 += p0; s1 += p1; s2 += p2;
            ac0 = fmaf(p0 * (d0.x + d0.y), xj0, ac0);
            ac1 = fmaf(p1 * (d1.x + d1.y), xj1, ac1);
            ac2 = fmaf(p2 * (d2.x + d2.y), xj2, ac2);
        }
        float* dstp = aggrN + (size_t)n * HCdim + lane;
        dstp[0]      = ac0 / (s0 + 1e-16f);
        dstp[CC]     = ac1 / (s1 + 1e-16f);
        dstp[2 * CC] = ac2 / (s2 + 1e-16f);
    }
}

// K5: out = aggrN @ Ws + bias, 16 staged rows, 4-row register blocking per wave.
#define K5_ROWS 16
__global__ __launch_bounds__(256) void tm_k5(const float* __restrict__ aggrN,
        const float* __restrict__ Ws, const float* __restrict__ bias,
        float* __restrict__ out, int N) {
    __shared__ float wsl[HCdim * CC];      // 48 KiB [k][c]
    __shared__ float al[K5_ROWS * HCdim];  // 12 KiB [r][k]
    const int t = threadIdx.x;
    const int part = t >> 6, c = t & 63;
    {
        float4* w4 = (float4*)wsl;
        const float4* Ws4 = (const float4*)Ws;
        for (int i = t; i < HCdim * CC / 4; i += 256) w4[i] = Ws4[i];
    }
    const float b = bias[c];
    const int base = blockIdx.x * K5_ROWS;
    const int rows = min(K5_ROWS, N - base);
    {
        float4* al4 = (float4*)al;
        const float4* a4 = (const float4*)(aggrN + (size_t)base * HCdim);
        for (int i = t; i < rows * HCdim / 4; i += 256) al4[i] = a4[i];
    }
    __syncthreads();
    const int r0 = part * 4;
    if (r0 >= rows) return;
    float acc0 = b, acc1 = b, acc2 = b, acc3 = b;
    #pragma unroll 4
    for (int k = 0; k < HCdim; k += 4) {
        const float w0  = wsl[(k + 0) * CC + c];
        const float w1  = wsl[(k + 1) * CC + c];
        const float w2_ = wsl[(k + 2) * CC + c];
        const float w3  = wsl[(k + 3) * CC + c];
        const float4 xa = *(const float4*)&al[(r0 + 0) * HCdim + k];
        const float4 xb = *(const float4*)&al[(r0 + 1) * HCdim + k];
        const float4 xc = *(const float4*)&al[(r0 + 2) * HCdim + k];
        const float4 xd = *(const float4*)&al[(r0 + 3) * HCdim + k];
        acc0 = fmaf(xa.x, w0, fmaf(xa.y, w1, fmaf(xa.z, w2_, fmaf(xa.w, w3, acc0))));
        acc1 = fmaf(xb.x, w0, fmaf(xb.y, w1, fmaf(xb.z, w2_, fmaf(xb.w, w3, acc1))));
        acc2 = fmaf(xc.x, w0, fmaf(xc.y, w1, fmaf(xc.z, w2_, fmaf(xc.w, w3, acc2))));
        acc3 = fmaf(xd.x, w0, fmaf(xd.y, w1, fmaf(xd.z, w2_, fmaf(xd.w, w3, acc3))));
    }
    if (r0 + 0 < rows) out[(size_t)(base + r0 + 0) * CC + c] = acc0;
    if (r0 + 1 < rows) out[(size_t)(base + r0 + 1) * CC + c] = acc1;
    if (r0 + 2 < rows) out[(size_t)(base + r0 + 2) * CC + c] = acc2;
    if (r0 + 3 < rows) out[(size_t)(base + r0 + 3) * CC + c] = acc3;
}

extern "C" void kernel_launch(void* const* d_in, const int* in_sizes, int n_in,
                              void* d_out, int out_size, void* d_ws, size_t ws_size,
                              hipStream_t stream) {
    const float* x    = (const float*)d_in[0];
    const int*   ei   = (const int*)d_in[1];
    const float* ea   = (const float*)d_in[2];
    const float* Wn   = (const float*)d_in[3];
    const float* We   = (const float*)d_in[4];
    const float* wt   = (const float*)d_in[5];
    const float* Ws   = (const float*)d_in[6];
    const float* bias = (const float*)d_in[7];
    float* out = (float*)d_out;
    const int N = in_sizes[0] / CC;
    const int E = in_sizes[1] / 2;
    const int nb = (N + 255) / 256;          // scan blocks (<= 256)

    // workspace layout (floats; 16B alignment kept for float4/int2 buffers)
    float* ws = (float*)d_ws;
    size_t o = 0;
    _Float16* xp16 = (_Float16*)(ws + o); o += (size_t)N * HCdim / 2;  // 19.2 MB
    float* sA = ws + o;                  o += (size_t)N * 8;       // 1.6 MB
    float* u  = ws + o;                  o += 128;
    float4* alphaE = (float4*)(ws + o);  o += (size_t)E * 4;       // 12.8 MB
    int2*  perm = (int2*)(ws + o);       o += (size_t)E * 2 + 32;
    int* deg    = (int*)(ws + o);        o += N;
    int* off    = (int*)(ws + o);        o += N + 1;
    int* cursor = (int*)(ws + o);        o += N;
    int* bsum   = (int*)(ws + o);        o += 256;
    int* boff   = (int*)(ws + o);        o += 256;
    o += (4 - (o & 3)) & 3;              // realign
    float* aggrN = ws + o;               o += (size_t)N * HCdim;   // 38.4 MB
    (void)ws_size; (void)n_in; (void)out_size;

    (void)hipMemsetAsync(deg, 0, (size_t)N * sizeof(int), stream);

    tm_k0<<<1, 96, 0, stream>>>(We, wt, u);
    tm_k1<<<(N + K1_ROWS - 1) / K1_ROWS, 192, 0, stream>>>(x, Wn, wt, ei, deg,
                                                           xp16, sA, N, E);
    tm_scanA<<<nb, 256, 0, stream>>>(deg, bsum, N);
    tm_scanB<<<1, 256, 0, stream>>>(bsum, boff, nb);
    tm_scanC<<<nb, 256, 0, stream>>>(deg, boff, off, cursor, N);
    tm_alpha<<<(E + 255) / 256, 256, 0, stream>>>(ei, ea, u, sA, cursor,
                                                  alphaE, perm, E);
    tm_agg<<<(N + 31) / 32, 256, 0, stream>>>(perm, off, ea, We,
                                              (const float*)alphaE, xp16, aggrN, N);
    tm_k5<<<(N + K5_ROWS - 1) / K5_ROWS, 256, 0, stream>>>(aggrN, Ws, bias, out, N);
}

// Round 14
// 408.542 us; speedup vs baseline: 1.0756x; 1.0756x over previous
//
#include <hip/hip_runtime.h>

#define CC    64
#define HH    3
#define ECC   32
#define HCdim 192
#define NEG_SLOPE 0.2f
#define ASHIFT 12.0f        // global softmax shift (shift-invariant)
#define LOG2E  1.44269504f

typedef float v2f __attribute__((ext_vector_type(2)));

// K0: u[h*32+k] = sum_c We[k*192 + h*64 + c] * wt[h*192 + 64 + c]
__global__ void tm_k0(const float* __restrict__ We, const float* __restrict__ wt,
                      float* __restrict__ u) {
    int t = threadIdx.x;
    if (t >= HH * ECC) return;
    int h = t >> 5, k = t & 31;
    float s = 0.f;
    #pragma unroll
    for (int c = 0; c < CC; ++c)
        s = fmaf(We[k * HCdim + h * CC + c], wt[h * HCdim + CC + c], s);
    u[t] = s;
}

// K1: xp(f16) = x @ Wn (N x 64 @ 64 x 192), 4-row register blocking,
// fused per-node scalars sA (f32) and deg histogram.
#define K1_ROWS 64
__global__ __launch_bounds__(192) void tm_k1(const float* __restrict__ x,
        const float* __restrict__ Wn, const float* __restrict__ wt,
        const int* __restrict__ ei, int* __restrict__ deg,
        _Float16* __restrict__ xp16, float* __restrict__ sA, int N, int E) {
    __shared__ float wl[CC * HCdim];     // 48 KiB [k][t]
    __shared__ float xl[K1_ROWS * CC];   // 16 KiB [r][k]
    const int t = threadIdx.x;
    // fused deg histogram over dst (overlaps GEMM; atomics retire async)
    for (int i = blockIdx.x * 192 + t; i < E; i += gridDim.x * 192)
        atomicAdd(&deg[ei[E + i]], 1);
    const int h = t >> 6, c = t & 63;
    {
        float4* wl4 = (float4*)wl;
        const float4* Wn4 = (const float4*)Wn;
        for (int i = t; i < CC * HCdim / 4; i += 192) wl4[i] = Wn4[i];
    }
    const int base = blockIdx.x * K1_ROWS;
    const int rows = min(K1_ROWS, N - base);
    {
        float4* xl4 = (float4*)xl;
        const float4* x4 = (const float4*)(x + (size_t)base * CC);
        for (int i = t; i < rows * CC / 4; i += 192) xl4[i] = x4[i];
    }
    const float w0c = wt[h * HCdim + c];
    const float w2c = wt[h * HCdim + 2 * CC + c];
    __syncthreads();
    for (int rt = 0; rt < rows; rt += 4) {
        float acc0 = 0.f, acc1 = 0.f, acc2 = 0.f, acc3 = 0.f;
        #pragma unroll 4
        for (int k = 0; k < CC; k += 4) {
            const float w0  = wl[(k + 0) * HCdim + t];
            const float w1  = wl[(k + 1) * HCdim + t];
            const float w2_ = wl[(k + 2) * HCdim + t];
            const float w3  = wl[(k + 3) * HCdim + t];
            const float4 xa = *(const float4*)&xl[(rt + 0) * CC + k];
            const float4 xb = *(const float4*)&xl[(rt + 1) * CC + k];
            const float4 xc = *(const float4*)&xl[(rt + 2) * CC + k];
            const float4 xd = *(const float4*)&xl[(rt + 3) * CC + k];
            acc0 = fmaf(xa.x, w0, fmaf(xa.y, w1, fmaf(xa.z, w2_, fmaf(xa.w, w3, acc0))));
            acc1 = fmaf(xb.x, w0, fmaf(xb.y, w1, fmaf(xb.z, w2_, fmaf(xb.w, w3, acc1))));
            acc2 = fmaf(xc.x, w0, fmaf(xc.y, w1, fmaf(xc.z, w2_, fmaf(xc.w, w3, acc2))));
            acc3 = fmaf(xd.x, w0, fmaf(xd.y, w1, fmaf(xd.z, w2_, fmaf(xd.w, w3, acc3))));
        }
        #pragma unroll
        for (int r = 0; r < 4; ++r) {
            const float v = (r == 0) ? acc0 : (r == 1) ? acc1 : (r == 2) ? acc2 : acc3;
            const int n = base + rt + r;
            xp16[(size_t)n * HCdim + t] = (_Float16)v;
            float a0 = v * w0c, a2 = v * w2c;
            #pragma unroll
            for (int o = 32; o; o >>= 1) {
                a0 += __shfl_xor(a0, o);
                a2 += __shfl_xor(a2, o);
            }
            if (c == 0) {
                sA[n * 8 + h]     = a0;
                sA[n * 8 + 4 + h] = a2;
            }
        }
    }
}

// scanA: per-block (256) sums of deg
__global__ __launch_bounds__(256) void tm_scanA(const int* __restrict__ deg,
        int* __restrict__ bsum, int N) {
    __shared__ int sd[256];
    int t = threadIdx.x, n = blockIdx.x * 256 + t;
    sd[t] = (n < N) ? deg[n] : 0;
    __syncthreads();
    for (int o = 128; o; o >>= 1) {
        if (t < o) sd[t] += sd[t + o];
        __syncthreads();
    }
    if (!t) bsum[blockIdx.x] = sd[0];
}

// scanB: exclusive scan of block sums (nb <= 256), single block
__global__ __launch_bounds__(256) void tm_scanB(const int* __restrict__ bsum,
        int* __restrict__ boff, int nb) {
    __shared__ int sd[256];
    int t = threadIdx.x;
    int v = (t < nb) ? bsum[t] : 0;
    sd[t] = v;
    __syncthreads();
    for (int o = 1; o < 256; o <<= 1) {
        int x = (t >= o) ? sd[t - o] : 0;
        __syncthreads();
        sd[t] += x;
        __syncthreads();
    }
    if (t < nb) boff[t] = sd[t] - v;   // exclusive
}

// scanC: per-element exclusive offsets; off[N]=E; cursor=off copy
__global__ __launch_bounds__(256) void tm_scanC(const int* __restrict__ deg,
        const int* __restrict__ boff, int* __restrict__ off,
        int* __restrict__ cursor, int N) {
    __shared__ int sd[256];
    int t = threadIdx.x, n = blockIdx.x * 256 + t;
    int v = (n < N) ? deg[n] : 0;
    sd[t] = v;
    __syncthreads();
    for (int o = 1; o < 256; o <<= 1) {
        int x = (t >= o) ? sd[t - o] : 0;
        __syncthreads();
        sd[t] += x;
        __syncthreads();
    }
    if (n < N) {
        int ex = boff[blockIdx.x] + sd[t] - v;
        off[n] = ex;
        cursor[n] = ex;
        if (n == N - 1) off[N] = ex + v;
    }
}

// K_alpha (+fused scatter): edge-order. alphaE now stores the PRE-EXPONENTIATED
// softmax weights p = e^(leaky(a)-ASHIFT) (identical numerics to exp in agg).
// perm = {src f16-row byte off, e ea byte off}.
__global__ __launch_bounds__(256) void tm_alpha(const int* __restrict__ ei,
        const float* __restrict__ ea, const float* __restrict__ u,
        const float* __restrict__ sA, int* __restrict__ cursor,
        float4* __restrict__ alphaE, int2* __restrict__ perm, int E) {
    __shared__ float ul[HH * ECC];
    const int t = threadIdx.x;
    if (t < HH * ECC) ul[t] = u[t];
    __syncthreads();
    const int e = blockIdx.x * 256 + t;
    if (e >= E) return;
    const int src = ei[e];
    const int dst = ei[E + e];
    float av[ECC];
    const float4* p4 = (const float4*)(ea + (size_t)e * ECC);
    #pragma unroll
    for (int q = 0; q < 8; ++q) {
        float4 v = p4[q];
        av[4*q] = v.x; av[4*q+1] = v.y; av[4*q+2] = v.z; av[4*q+3] = v.w;
    }
    float d0 = 0.f, d1 = 0.f, d2 = 0.f;
    #pragma unroll
    for (int k = 0; k < ECC; ++k) {
        d0 = fmaf(av[k], ul[k], d0);
        d1 = fmaf(av[k], ul[ECC + k], d1);
        d2 = fmaf(av[k], ul[2 * ECC + k], d2);
    }
    const float4 s0 = *(const float4*)(sA + (size_t)dst * 8);
    const float4 s2 = *(const float4*)(sA + (size_t)src * 8 + 4);
    float a0 = s0.x + d0 + s2.x;
    float a1 = s0.y + d1 + s2.y;
    float a2 = s0.z + d2 + s2.z;
    a0 = (a0 >= 0.f) ? a0 : NEG_SLOPE * a0;
    a1 = (a1 >= 0.f) ? a1 : NEG_SLOPE * a1;
    a2 = (a2 >= 0.f) ? a2 : NEG_SLOPE * a2;
    alphaE[e] = make_float4(exp2f((a0 - ASHIFT) * LOG2E),
                            exp2f((a1 - ASHIFT) * LOG2E),
                            exp2f((a2 - ASHIFT) * LOG2E), 0.f);
    const int pos = atomicAdd(&cursor[dst], 1);
    perm[pos] = make_int2(src * (HCdim * 2), e * (ECC * 4));
}

// K_agg: R11 structure (proven): 3 waves = 3 heads per block, grid-strided
// nodes, 2-edge unroll, perm prefetch, f16 xj. alphaE is pre-exponentiated.
__global__ __launch_bounds__(192) void tm_agg(const int2* __restrict__ perm,
        const int* __restrict__ off, const float* __restrict__ ea,
        const float* __restrict__ We, const float* __restrict__ alphaE,
        const _Float16* __restrict__ xp16, float* __restrict__ aggrN, int N) {
    const int t = threadIdx.x;
    const int h = t >> 6, lane = t & 63;
    const char* __restrict__ ea_b = (const char*)ea;
    const char* __restrict__ xp_b = (const char*)xp16;
    const char* __restrict__ al_b = (const char*)alphaE;
    v2f wcol2[16];
    #pragma unroll
    for (int k2 = 0; k2 < 16; ++k2) {
        wcol2[k2].x = We[(2 * k2)     * HCdim + h * CC + lane];
        wcol2[k2].y = We[(2 * k2 + 1) * HCdim + h * CC + lane];
    }
    const int xoff = h * (CC * 2) + lane * 2;  // byte offset within f16 xp row
    const int aoff = h * 4;                    // byte offset within alphaE entry
    for (int n = blockIdx.x; n < N; n += gridDim.x) {
        const int start = off[n], end = off[n + 1];
        float s = 0.f, acc = 0.f;
        int pos = start;
        int4 pp = (pos + 2 <= end) ? *(const int4*)&perm[pos]
                                   : make_int4(0, 0, 0, 0);
        for (; pos + 2 <= end; ) {
            const int4 cur = pp;
            pos += 2;
            if (pos + 2 <= end) pp = *(const int4*)&perm[pos];
            const int so0 = __builtin_amdgcn_readfirstlane(cur.x);
            const int eo0 = __builtin_amdgcn_readfirstlane(cur.y);
            const int so1 = __builtin_amdgcn_readfirstlane(cur.z);
            const int eo1 = __builtin_amdgcn_readfirstlane(cur.w);
            const float p0 = *(const float*)(al_b + (eo0 >> 3) + aoff);
            const float p1 = *(const float*)(al_b + (eo1 >> 3) + aoff);
            const float4* q0 = (const float4*)(ea_b + eo0);
            const float4* q1 = (const float4*)(ea_b + eo1);
            const float xj0 = (float)*(const _Float16*)(xp_b + so0 + xoff);
            const float xj1 = (float)*(const _Float16*)(xp_b + so1 + xoff);
            v2f d0 = {0.f, 0.f}, d1 = {0.f, 0.f};
            #pragma unroll
            for (int q = 0; q < 8; ++q) {
                const float4 v0 = q0[q];
                const float4 v1 = q1[q];
                const v2f wlo = wcol2[2 * q], whi = wcol2[2 * q + 1];
                d0 = (v2f){v0.x, v0.y} * wlo + d0;
                d0 = (v2f){v0.z, v0.w} * whi + d0;
                d1 = (v2f){v1.x, v1.y} * wlo + d1;
                d1 = (v2f){v1.z, v1.w} * whi + d1;
            }
            s += p0 + p1;
            acc = fmaf(p0 * (d0.x + d0.y), xj0, acc);
            acc = fmaf(p1 * (d1.x + d1.y), xj1, acc);
        }
        if (pos < end) {
            const int2 pe = perm[pos];
            const int so = __builtin_amdgcn_readfirstlane(pe.x);
            const int eo = __builtin_amdgcn_readfirstlane(pe.y);
            const float p = *(const float*)(al_b + (eo >> 3) + aoff);
            const float4* q4 = (const float4*)(ea_b + eo);
            const float xj = (float)*(const _Float16*)(xp_b + so + xoff);
            v2f d = {0.f, 0.f};
            #pragma unroll
            for (int q = 0; q < 8; ++q) {
                const float4 v = q4[q];
                d = (v2f){v.x, v.y} * wcol2[2 * q]     + d;
                d = (v2f){v.z, v.w} * wcol2[2 * q + 1] + d;
            }
            s += p;
            acc = fmaf(p * (d.x + d.y), xj, acc);
        }
        aggrN[(size_t)n * HCdim + h * CC + lane] = acc / (s + 1e-16f);
    }
}

// K5: out = aggrN @ Ws + bias; Ws staged once per block, grid-strided tiles.
#define K5_ROWS 16
__global__ __launch_bounds__(256) void tm_k5(const float* __restrict__ aggrN,
        const float* __restrict__ Ws, const float* __restrict__ bias,
        float* __restrict__ out, int N) {
    __shared__ float wsl[HCdim * CC];      // 48 KiB [k][c]
    __shared__ float al[K5_ROWS * HCdim];  // 12 KiB [r][k]
    const int t = threadIdx.x;
    const int part = t >> 6, c = t & 63;
    {
        float4* w4 = (float4*)wsl;
        const float4* Ws4 = (const float4*)Ws;
        for (int i = t; i < HCdim * CC / 4; i += 256) w4[i] = Ws4[i];
    }
    const float b = bias[c];
    for (int base = blockIdx.x * K5_ROWS; base < N; base += gridDim.x * K5_ROWS) {
        const int rows = min(K5_ROWS, N - base);
        __syncthreads();   // Ws staged (iter 0) / prior tile compute done
        {
            float4* al4 = (float4*)al;
            const float4* a4 = (const float4*)(aggrN + (size_t)base * HCdim);
            for (int i = t; i < rows * HCdim / 4; i += 256) al4[i] = a4[i];
        }
        __syncthreads();
        const int r0 = part * 4;
        if (r0 >= rows) continue;
        float acc0 = b, acc1 = b, acc2 = b, acc3 = b;
        #pragma unroll 4
        for (int k = 0; k < HCdim; k += 4) {
            const float w0  = wsl[(k + 0) * CC + c];
            const float w1  = wsl[(k + 1) * CC + c];
            const float w2_ = wsl[(k + 2) * CC + c];
            const float w3  = wsl[(k + 3) * CC + c];
            const float4 xa = *(const float4*)&al[(r0 + 0) * HCdim + k];
            const float4 xb = *(const float4*)&al[(r0 + 1) * HCdim + k];
            const float4 xc = *(const float4*)&al[(r0 + 2) * HCdim + k];
            const float4 xd = *(const float4*)&al[(r0 + 3) * HCdim + k];
            acc0 = fmaf(xa.x, w0, fmaf(xa.y, w1, fmaf(xa.z, w2_, fmaf(xa.w, w3, acc0))));
            acc1 = fmaf(xb.x, w0, fmaf(xb.y, w1, fmaf(xb.z, w2_, fmaf(xb.w, w3, acc1))));
            acc2 = fmaf(xc.x, w0, fmaf(xc.y, w1, fmaf(xc.z, w2_, fmaf(xc.w, w3, acc2))));
            acc3 = fmaf(xd.x, w0, fmaf(xd.y, w1, fmaf(xd.z, w2_, fmaf(xd.w, w3, acc3))));
        }
        if (r0 + 0 < rows) out[(size_t)(base + r0 + 0) * CC + c] = acc0;
        if (r0 + 1 < rows) out[(size_t)(base + r0 + 1) * CC + c] = acc1;
        if (r0 + 2 < rows) out[(size_t)(base + r0 + 2) * CC + c] = acc2;
        if (r0 + 3 < rows) out[(size_t)(base + r0 + 3) * CC + c] = acc3;
    }
}

extern "C" void kernel_launch(void* const* d_in, const int* in_sizes, int n_in,
                              void* d_out, int out_size, void* d_ws, size_t ws_size,
                              hipStream_t stream) {
    const float* x    = (const float*)d_in[0];
    const int*   ei   = (const int*)d_in[1];
    const float* ea   = (const float*)d_in[2];
    const float* Wn   = (const float*)d_in[3];
    const float* We   = (const float*)d_in[4];
    const float* wt   = (const float*)d_in[5];
    const float* Ws   = (const float*)d_in[6];
    const float* bias = (const float*)d_in[7];
    float* out = (float*)d_out;
    const int N = in_sizes[0] / CC;
    const int E = in_sizes[1] / 2;
    const int nb = (N + 255) / 256;          // scan blocks (<= 256)

    // workspace layout (floats; 16B alignment kept for float4/int2 buffers)
    float* ws = (float*)d_ws;
    size_t o = 0;
    _Float16* xp16 = (_Float16*)(ws + o); o += (size_t)N * HCdim / 2;  // 19.2 MB
    float* sA = ws + o;                  o += (size_t)N * 8;       // 1.6 MB
    float* u  = ws + o;                  o += 128;
    float4* alphaE = (float4*)(ws + o);  o += (size_t)E * 4;       // 12.8 MB
    int2*  perm = (int2*)(ws + o);       o += (size_t)E * 2 + 32;
    int* deg    = (int*)(ws + o);        o += N;
    int* off    = (int*)(ws + o);        o += N + 1;
    int* cursor = (int*)(ws + o);        o += N;
    int* bsum   = (int*)(ws + o);        o += 256;
    int* boff   = (int*)(ws + o);        o += 256;
    o += (4 - (o & 3)) & 3;              // realign
    float* aggrN = ws + o;               o += (size_t)N * HCdim;   // 38.4 MB
    (void)ws_size; (void)n_in; (void)out_size;

    (void)hipMemsetAsync(deg, 0, (size_t)N * sizeof(int), stream);

    tm_k0<<<1, 96, 0, stream>>>(We, wt, u);
    tm_k1<<<(N + K1_ROWS - 1) / K1_ROWS, 192, 0, stream>>>(x, Wn, wt, ei, deg,
                                                           xp16, sA, N, E);
    tm_scanA<<<nb, 256, 0, stream>>>(deg, bsum, N);
    tm_scanB<<<1, 256, 0, stream>>>(bsum, boff, nb);
    tm_scanC<<<nb, 256, 0, stream>>>(deg, boff, off, cursor, N);
    tm_alpha<<<(E + 255) / 256, 256, 0, stream>>>(ei, ea, u, sA, cursor,
                                                  alphaE, perm, E);
    tm_agg<<<(N + 7) / 8, 192, 0, stream>>>(perm, off, ea, We,
                                            (const float*)alphaE, xp16, aggrN, N);
    tm_k5<<<512, 256, 0, stream>>>(aggrN, Ws, bias, out, N);
}

// Round 15
// 383.961 us; speedup vs baseline: 1.1445x; 1.0640x over previous
//
#include <hip/hip_runtime.h>

#define CC    64
#define HH    3
#define ECC   32
#define HCdim 192
#define NEG_SLOPE 0.2f
#define ASHIFT 12.0f        // global softmax shift (shift-invariant)
#define LOG2E  1.44269504f

typedef float v2f __attribute__((ext_vector_type(2)));
typedef _Float16 h2 __attribute__((ext_vector_type(2)));
typedef _Float16 h8 __attribute__((ext_vector_type(8)));

#if defined(__has_builtin)
#  if __has_builtin(__builtin_amdgcn_fdot2)
#    define USE_FDOT2 1
#  endif
#endif
#ifndef USE_FDOT2
#  define USE_FDOT2 0
#endif

// K0: u[h*32+k] = sum_c We[k*192 + h*64 + c] * wt[h*192 + 64 + c]
__global__ void tm_k0(const float* __restrict__ We, const float* __restrict__ wt,
                      float* __restrict__ u) {
    int t = threadIdx.x;
    if (t >= HH * ECC) return;
    int h = t >> 5, k = t & 31;
    float s = 0.f;
    #pragma unroll
    for (int c = 0; c < CC; ++c)
        s = fmaf(We[k * HCdim + h * CC + c], wt[h * HCdim + CC + c], s);
    u[t] = s;
}

// K1: xp(f16) = x @ Wn (N x 64 @ 64 x 192), 4-row register blocking,
// fused per-node scalars sA (f32) and deg histogram.
#define K1_ROWS 64
__global__ __launch_bounds__(192) void tm_k1(const float* __restrict__ x,
        const float* __restrict__ Wn, const float* __restrict__ wt,
        const int* __restrict__ ei, int* __restrict__ deg,
        _Float16* __restrict__ xp16, float* __restrict__ sA, int N, int E) {
    __shared__ float wl[CC * HCdim];     // 48 KiB [k][t]
    __shared__ float xl[K1_ROWS * CC];   // 16 KiB [r][k]
    const int t = threadIdx.x;
    // fused deg histogram over dst (overlaps GEMM; atomics retire async)
    for (int i = blockIdx.x * 192 + t; i < E; i += gridDim.x * 192)
        atomicAdd(&deg[ei[E + i]], 1);
    const int h = t >> 6, c = t & 63;
    {
        float4* wl4 = (float4*)wl;
        const float4* Wn4 = (const float4*)Wn;
        for (int i = t; i < CC * HCdim / 4; i += 192) wl4[i] = Wn4[i];
    }
    const int base = blockIdx.x * K1_ROWS;
    const int rows = min(K1_ROWS, N - base);
    {
        float4* xl4 = (float4*)xl;
        const float4* x4 = (const float4*)(x + (size_t)base * CC);
        for (int i = t; i < rows * CC / 4; i += 192) xl4[i] = x4[i];
    }
    const float w0c = wt[h * HCdim + c];
    const float w2c = wt[h * HCdim + 2 * CC + c];
    __syncthreads();
    for (int rt = 0; rt < rows; rt += 4) {
        float acc0 = 0.f, acc1 = 0.f, acc2 = 0.f, acc3 = 0.f;
        #pragma unroll 4
        for (int k = 0; k < CC; k += 4) {
            const float w0  = wl[(k + 0) * HCdim + t];
            const float w1  = wl[(k + 1) * HCdim + t];
            const float w2_ = wl[(k + 2) * HCdim + t];
            const float w3  = wl[(k + 3) * HCdim + t];
            const float4 xa = *(const float4*)&xl[(rt + 0) * CC + k];
            const float4 xb = *(const float4*)&xl[(rt + 1) * CC + k];
            const float4 xc = *(const float4*)&xl[(rt + 2) * CC + k];
            const float4 xd = *(const float4*)&xl[(rt + 3) * CC + k];
            acc0 = fmaf(xa.x, w0, fmaf(xa.y, w1, fmaf(xa.z, w2_, fmaf(xa.w, w3, acc0))));
            acc1 = fmaf(xb.x, w0, fmaf(xb.y, w1, fmaf(xb.z, w2_, fmaf(xb.w, w3, acc1))));
            acc2 = fmaf(xc.x, w0, fmaf(xc.y, w1, fmaf(xc.z, w2_, fmaf(xc.w, w3, acc2))));
            acc3 = fmaf(xd.x, w0, fmaf(xd.y, w1, fmaf(xd.z, w2_, fmaf(xd.w, w3, acc3))));
        }
        #pragma unroll
        for (int r = 0; r < 4; ++r) {
            const float v = (r == 0) ? acc0 : (r == 1) ? acc1 : (r == 2) ? acc2 : acc3;
            const int n = base + rt + r;
            xp16[(size_t)n * HCdim + t] = (_Float16)v;
            float a0 = v * w0c, a2 = v * w2c;
            #pragma unroll
            for (int o = 32; o; o >>= 1) {
                a0 += __shfl_xor(a0, o);
                a2 += __shfl_xor(a2, o);
            }
            if (c == 0) {
                sA[n * 8 + h]     = a0;
                sA[n * 8 + 4 + h] = a2;
            }
        }
    }
}

// scanA: per-block (256) sums of deg
__global__ __launch_bounds__(256) void tm_scanA(const int* __restrict__ deg,
        int* __restrict__ bsum, int N) {
    __shared__ int sd[256];
    int t = threadIdx.x, n = blockIdx.x * 256 + t;
    sd[t] = (n < N) ? deg[n] : 0;
    __syncthreads();
    for (int o = 128; o; o >>= 1) {
        if (t < o) sd[t] += sd[t + o];
        __syncthreads();
    }
    if (!t) bsum[blockIdx.x] = sd[0];
}

// scanB: exclusive scan of block sums (nb <= 256), single block
__global__ __launch_bounds__(256) void tm_scanB(const int* __restrict__ bsum,
        int* __restrict__ boff, int nb) {
    __shared__ int sd[256];
    int t = threadIdx.x;
    int v = (t < nb) ? bsum[t] : 0;
    sd[t] = v;
    __syncthreads();
    for (int o = 1; o < 256; o <<= 1) {
        int x = (t >= o) ? sd[t - o] : 0;
        __syncthreads();
        sd[t] += x;
        __syncthreads();
    }
    if (t < nb) boff[t] = sd[t] - v;   // exclusive
}

// scanC: per-element exclusive offsets; off[N]=E; cursor=off copy
__global__ __launch_bounds__(256) void tm_scanC(const int* __restrict__ deg,
        const int* __restrict__ boff, int* __restrict__ off,
        int* __restrict__ cursor, int N) {
    __shared__ int sd[256];
    int t = threadIdx.x, n = blockIdx.x * 256 + t;
    int v = (n < N) ? deg[n] : 0;
    sd[t] = v;
    __syncthreads();
    for (int o = 1; o < 256; o <<= 1) {
        int x = (t >= o) ? sd[t - o] : 0;
        __syncthreads();
        sd[t] += x;
        __syncthreads();
    }
    if (n < N) {
        int ex = boff[blockIdx.x] + sd[t] - v;
        off[n] = ex;
        cursor[n] = ex;
        if (n == N - 1) off[N] = ex + v;
    }
}

// K_alpha (+fused scatter): edge-order. alphaE stores PRE-EXPONENTIATED
// weights p = e^(leaky(a)-ASHIFT). Also emits ea16 (f16 copy of the edge row,
// coalesced) for agg's fdot2 path. perm = {src f16-row byte off, e ea byte off}.
__global__ __launch_bounds__(256) void tm_alpha(const int* __restrict__ ei,
        const float* __restrict__ ea, const float* __restrict__ u,
        const float* __restrict__ sA, int* __restrict__ cursor,
        float4* __restrict__ alphaE, int2* __restrict__ perm,
        _Float16* __restrict__ ea16, int E) {
    __shared__ float ul[HH * ECC];
    const int t = threadIdx.x;
    if (t < HH * ECC) ul[t] = u[t];
    __syncthreads();
    const int e = blockIdx.x * 256 + t;
    if (e >= E) return;
    const int src = ei[e];
    const int dst = ei[E + e];
    float av[ECC];
    const float4* p4 = (const float4*)(ea + (size_t)e * ECC);
    #pragma unroll
    for (int q = 0; q < 8; ++q) {
        float4 v = p4[q];
        av[4*q] = v.x; av[4*q+1] = v.y; av[4*q+2] = v.z; av[4*q+3] = v.w;
    }
#if USE_FDOT2
    {   // f16 copy of this edge's row (coalesced 64B store)
        h8* dst16 = (h8*)(ea16 + (size_t)e * ECC);
        #pragma unroll
        for (int b = 0; b < 4; ++b) {
            h8 o16;
            #pragma unroll
            for (int j = 0; j < 8; ++j) o16[j] = (_Float16)av[b * 8 + j];
            dst16[b] = o16;
        }
    }
#else
    (void)ea16;
#endif
    float d0 = 0.f, d1 = 0.f, d2 = 0.f;
    #pragma unroll
    for (int k = 0; k < ECC; ++k) {
        d0 = fmaf(av[k], ul[k], d0);
        d1 = fmaf(av[k], ul[ECC + k], d1);
        d2 = fmaf(av[k], ul[2 * ECC + k], d2);
    }
    const float4 s0 = *(const float4*)(sA + (size_t)dst * 8);
    const float4 s2 = *(const float4*)(sA + (size_t)src * 8 + 4);
    float a0 = s0.x + d0 + s2.x;
    float a1 = s0.y + d1 + s2.y;
    float a2 = s0.z + d2 + s2.z;
    a0 = (a0 >= 0.f) ? a0 : NEG_SLOPE * a0;
    a1 = (a1 >= 0.f) ? a1 : NEG_SLOPE * a1;
    a2 = (a2 >= 0.f) ? a2 : NEG_SLOPE * a2;
    alphaE[e] = make_float4(exp2f((a0 - ASHIFT) * LOG2E),
                            exp2f((a1 - ASHIFT) * LOG2E),
                            exp2f((a2 - ASHIFT) * LOG2E), 0.f);
    const int pos = atomicAdd(&cursor[dst], 1);
    perm[pos] = make_int2(src * (HCdim * 2), e * (ECC * 4));
}

// K_agg: R11 structure: 3 waves = 3 heads per block, grid-strided nodes,
// 2-edge unroll, perm prefetch, f16 xj, pre-exp alpha. Dot via fdot2 on the
// f16 ea copy (half the uniform-row loads/bytes); f32 pk_fma fallback.
__global__ __launch_bounds__(192) void tm_agg(const int2* __restrict__ perm,
        const int* __restrict__ off, const float* __restrict__ ea,
        const float* __restrict__ We, const float* __restrict__ alphaE,
        const _Float16* __restrict__ xp16, const _Float16* __restrict__ ea16,
        float* __restrict__ aggrN, int N) {
    const int t = threadIdx.x;
    const int h = t >> 6, lane = t & 63;
    const char* __restrict__ xp_b = (const char*)xp16;
    const char* __restrict__ al_b = (const char*)alphaE;
#if USE_FDOT2
    const char* __restrict__ e16_b = (const char*)ea16;
    h2 wc[16];   // 16 VGPR: f16 pairs of this lane's We column
    #pragma unroll
    for (int k2 = 0; k2 < 16; ++k2) {
        h2 w;
        w[0] = (_Float16)We[(2 * k2)     * HCdim + h * CC + lane];
        w[1] = (_Float16)We[(2 * k2 + 1) * HCdim + h * CC + lane];
        wc[k2] = w;
    }
#else
    const char* __restrict__ ea_b = (const char*)ea;
    (void)ea16;
    v2f wcol2[16];
    #pragma unroll
    for (int k2 = 0; k2 < 16; ++k2) {
        wcol2[k2].x = We[(2 * k2)     * HCdim + h * CC + lane];
        wcol2[k2].y = We[(2 * k2 + 1) * HCdim + h * CC + lane];
    }
#endif
    const int xoff = h * (CC * 2) + lane * 2;  // byte offset within f16 xp row
    const int aoff = h * 4;                    // byte offset within alphaE entry
    for (int n = blockIdx.x; n < N; n += gridDim.x) {
        const int start = off[n], end = off[n + 1];
        float s = 0.f, acc = 0.f;
        int pos = start;
        int4 pp = (pos + 2 <= end) ? *(const int4*)&perm[pos]
                                   : make_int4(0, 0, 0, 0);
        for (; pos + 2 <= end; ) {
            const int4 cur = pp;
            pos += 2;
            if (pos + 2 <= end) pp = *(const int4*)&perm[pos];
            const int so0 = __builtin_amdgcn_readfirstlane(cur.x);
            const int eo0 = __builtin_amdgcn_readfirstlane(cur.y);
            const int so1 = __builtin_amdgcn_readfirstlane(cur.z);
            const int eo1 = __builtin_amdgcn_readfirstlane(cur.w);
            const float p0 = *(const float*)(al_b + (eo0 >> 3) + aoff);
            const float p1 = *(const float*)(al_b + (eo1 >> 3) + aoff);
            const float xj0 = (float)*(const _Float16*)(xp_b + so0 + xoff);
            const float xj1 = (float)*(const _Float16*)(xp_b + so1 + xoff);
            float ep0, ep1;
#if USE_FDOT2
            const uint4 a0 = *(const uint4*)(e16_b + (eo0 >> 1));
            const uint4 a1 = *(const uint4*)(e16_b + (eo0 >> 1) + 16);
            const uint4 b0 = *(const uint4*)(e16_b + (eo1 >> 1));
            const uint4 b1 = *(const uint4*)(e16_b + (eo1 >> 1) + 16);
            float d0 = 0.f, d1 = 0.f;
            d0 = __builtin_amdgcn_fdot2(__builtin_bit_cast(h2, a0.x), wc[0], d0, false);
            d0 = __builtin_amdgcn_fdot2(__builtin_bit_cast(h2, a0.y), wc[1], d0, false);
            d0 = __builtin_amdgcn_fdot2(__builtin_bit_cast(h2, a0.z), wc[2], d0, false);
            d0 = __builtin_amdgcn_fdot2(__builtin_bit_cast(h2, a0.w), wc[3], d0, false);
            d0 = __builtin_amdgcn_fdot2(__builtin_bit_cast(h2, a1.x), wc[4], d0, false);
            d0 = __builtin_amdgcn_fdot2(__builtin_bit_cast(h2, a1.y), wc[5], d0, false);
            d0 = __builtin_amdgcn_fdot2(__builtin_bit_cast(h2, a1.z), wc[6], d0, false);
            d0 = __builtin_amdgcn_fdot2(__builtin_bit_cast(h2, a1.w), wc[7], d0, false);
            const uint4 a2 = *(const uint4*)(e16_b + (eo0 >> 1) + 32);
            const uint4 a3 = *(const uint4*)(e16_b + (eo0 >> 1) + 48);
            d0 = __builtin_amdgcn_fdot2(__builtin_bit_cast(h2, a2.x), wc[8],  d0, false);
            d0 = __builtin_amdgcn_fdot2(__builtin_bit_cast(h2, a2.y), wc[9],  d0, false);
            d0 = __builtin_amdgcn_fdot2(__builtin_bit_cast(h2, a2.z), wc[10], d0, false);
            d0 = __builtin_amdgcn_fdot2(__builtin_bit_cast(h2, a2.w), wc[11], d0, false);
            d0 = __builtin_amdgcn_fdot2(__builtin_bit_cast(h2, a3.x), wc[12], d0, false);
            d0 = __builtin_amdgcn_fdot2(__builtin_bit_cast(h2, a3.y), wc[13], d0, false);
            d0 = __builtin_amdgcn_fdot2(__builtin_bit_cast(h2, a3.z), wc[14], d0, false);
            d0 = __builtin_amdgcn_fdot2(__builtin_bit_cast(h2, a3.w), wc[15], d0, false);
            const uint4 b2 = *(const uint4*)(e16_b + (eo1 >> 1) + 32);
            const uint4 b3 = *(const uint4*)(e16_b + (eo1 >> 1) + 48);
            d1 = __builtin_amdgcn_fdot2(__builtin_bit_cast(h2, b0.x), wc[0],  d1, false);
            d1 = __builtin_amdgcn_fdot2(__builtin_bit_cast(h2, b0.y), wc[1],  d1, false);
            d1 = __builtin_amdgcn_fdot2(__builtin_bit_cast(h2, b0.z), wc[2],  d1, false);
            d1 = __builtin_amdgcn_fdot2(__builtin_bit_cast(h2, b0.w), wc[3],  d1, false);
            d1 = __builtin_amdgcn_fdot2(__builtin_bit_cast(h2, b1.x), wc[4],  d1, false);
            d1 = __builtin_amdgcn_fdot2(__builtin_bit_cast(h2, b1.y), wc[5],  d1, false);
            d1 = __builtin_amdgcn_fdot2(__builtin_bit_cast(h2, b1.z), wc[6],  d1, false);
            d1 = __builtin_amdgcn_fdot2(__builtin_bit_cast(h2, b1.w), wc[7],  d1, false);
            d1 = __builtin_amdgcn_fdot2(__builtin_bit_cast(h2, b2.x), wc[8],  d1, false);
            d1 = __builtin_amdgcn_fdot2(__builtin_bit_cast(h2, b2.y), wc[9],  d1, false);
            d1 = __builtin_amdgcn_fdot2(__builtin_bit_cast(h2, b2.z), wc[10], d1, false);
            d1 = __builtin_amdgcn_fdot2(__builtin_bit_cast(h2, b2.w), wc[11], d1, false);
            d1 = __builtin_amdgcn_fdot2(__builtin_bit_cast(h2, b3.x), wc[12], d1, false);
            d1 = __builtin_amdgcn_fdot2(__builtin_bit_cast(h2, b3.y), wc[13], d1, false);
            d1 = __builtin_amdgcn_fdot2(__builtin_bit_cast(h2, b3.z), wc[14], d1, false);
            d1 = __builtin_amdgcn_fdot2(__builtin_bit_cast(h2, b3.w), wc[15], d1, false);
            ep0 = d0; ep1 = d1;
#else
            const float4* q0 = (const float4*)(ea_b + eo0);
            const float4* q1 = (const float4*)(ea_b + eo1);
            v2f d0 = {0.f, 0.f}, d1 = {0.f, 0.f};
            #pragma unroll
            for (int q = 0; q < 8; ++q) {
                const float4 v0 = q0[q];
                const float4 v1 = q1[q];
                const v2f wlo = wcol2[2 * q], whi = wcol2[2 * q + 1];
                d0 = (v2f){v0.x, v0.y} * wlo + d0;
                d0 = (v2f){v0.z, v0.w} * whi + d0;
                d1 = (v2f){v1.x, v1.y} * wlo + d1;
                d1 = (v2f){v1.z, v1.w} * whi + d1;
            }
            ep0 = d0.x + d0.y; ep1 = d1.x + d1.y;
#endif
            s += p0 + p1;
            acc = fmaf(p0 * ep0, xj0, acc);
            acc = fmaf(p1 * ep1, xj1, acc);
        }
        if (pos < end) {
            const int2 pe = perm[pos];
            const int so = __builtin_amdgcn_readfirstlane(pe.x);
            const int eo = __builtin_amdgcn_readfirstlane(pe.y);
            const float p = *(const float*)(al_b + (eo >> 3) + aoff);
            const float xj = (float)*(const _Float16*)(xp_b + so + xoff);
            float ep;
#if USE_FDOT2
            const uint4 a0 = *(const uint4*)(e16_b + (eo >> 1));
            const uint4 a1 = *(const uint4*)(e16_b + (eo >> 1) + 16);
            const uint4 a2 = *(const uint4*)(e16_b + (eo >> 1) + 32);
            const uint4 a3 = *(const uint4*)(e16_b + (eo >> 1) + 48);
            float d = 0.f;
            d = __builtin_amdgcn_fdot2(__builtin_bit_cast(h2, a0.x), wc[0],  d, false);
            d = __builtin_amdgcn_fdot2(__builtin_bit_cast(h2, a0.y), wc[1],  d, false);
            d = __builtin_amdgcn_fdot2(__builtin_bit_cast(h2, a0.z), wc[2],  d, false);
            d = __builtin_amdgcn_fdot2(__builtin_bit_cast(h2, a0.w), wc[3],  d, false);
            d = __builtin_amdgcn_fdot2(__builtin_bit_cast(h2, a1.x), wc[4],  d, false);
            d = __builtin_amdgcn_fdot2(__builtin_bit_cast(h2, a1.y), wc[5],  d, false);
            d = __builtin_amdgcn_fdot2(__builtin_bit_cast(h2, a1.z), wc[6],  d, false);
            d = __builtin_amdgcn_fdot2(__builtin_bit_cast(h2, a1.w), wc[7],  d, false);
            d = __builtin_amdgcn_fdot2(__builtin_bit_cast(h2, a2.x), wc[8],  d, false);
            d = __builtin_amdgcn_fdot2(__builtin_bit_cast(h2, a2.y), wc[9],  d, false);
            d = __builtin_amdgcn_fdot2(__builtin_bit_cast(h2, a2.z), wc[10], d, false);
            d = __builtin_amdgcn_fdot2(__builtin_bit_cast(h2, a2.w), wc[11], d, false);
            d = __builtin_amdgcn_fdot2(__builtin_bit_cast(h2, a3.x), wc[12], d, false);
            d = __builtin_amdgcn_fdot2(__builtin_bit_cast(h2, a3.y), wc[13], d, false);
            d = __builtin_amdgcn_fdot2(__builtin_bit_cast(h2, a3.z), wc[14], d, false);
            d = __builtin_amdgcn_fdot2(__builtin_bit_cast(h2, a3.w), wc[15], d, false);
            ep = d;
#else
            const float4* q4 = (const float4*)(ea_b + eo);
            v2f d = {0.f, 0.f};
            #pragma unroll
            for (int q = 0; q < 8; ++q) {
                const float4 v = q4[q];
                d = (v2f){v.x, v.y} * wcol2[2 * q]     + d;
                d = (v2f){v.z, v.w} * wcol2[2 * q + 1] + d;
            }
            ep = d.x + d.y;
#endif
            s += p;
            acc = fmaf(p * ep, xj, acc);
        }
        aggrN[(size_t)n * HCdim + h * CC + lane] = acc / (s + 1e-16f);
    }
}

// K5: out = aggrN @ Ws + bias; Ws staged once per block, grid-strided tiles.
#define K5_ROWS 16
__global__ __launch_bounds__(256) void tm_k5(const float* __restrict__ aggrN,
        const float* __restrict__ Ws, const float* __restrict__ bias,
        float* __restrict__ out, int N) {
    __shared__ float wsl[HCdim * CC];      // 48 KiB [k][c]
    __shared__ float al[K5_ROWS * HCdim];  // 12 KiB [r][k]
    const int t = threadIdx.x;
    const int part = t >> 6, c = t & 63;
    {
        float4* w4 = (float4*)wsl;
        const float4* Ws4 = (const float4*)Ws;
        for (int i = t; i < HCdim * CC / 4; i += 256) w4[i] = Ws4[i];
    }
    const float b = bias[c];
    for (int base = blockIdx.x * K5_ROWS; base < N; base += gridDim.x * K5_ROWS) {
        const int rows = min(K5_ROWS, N - base);
        __syncthreads();   // Ws staged (iter 0) / prior tile compute done
        {
            float4* al4 = (float4*)al;
            const float4* a4 = (const float4*)(aggrN + (size_t)base * HCdim);
            for (int i = t; i < rows * HCdim / 4; i += 256) al4[i] = a4[i];
        }
        __syncthreads();
        const int r0 = part * 4;
        if (r0 >= rows) continue;
        float acc0 = b, acc1 = b, acc2 = b, acc3 = b;
        #pragma unroll 4
        for (int k = 0; k < HCdim; k += 4) {
            const float w0  = wsl[(k + 0) * CC + c];
            const float w1  = wsl[(k + 1) * CC + c];
            const float w2_ = wsl[(k + 2) * CC + c];
            const float w3  = wsl[(k + 3) * CC + c];
            const float4 xa = *(const float4*)&al[(r0 + 0) * HCdim + k];
            const float4 xb = *(const float4*)&al[(r0 + 1) * HCdim + k];
            const float4 xc = *(const float4*)&al[(r0 + 2) * HCdim + k];
            const float4 xd = *(const float4*)&al[(r0 + 3) * HCdim + k];
            acc0 = fmaf(xa.x, w0, fmaf(xa.y, w1, fmaf(xa.z, w2_, fmaf(xa.w, w3, acc0))));
            acc1 = fmaf(xb.x, w0, fmaf(xb.y, w1, fmaf(xb.z, w2_, fmaf(xb.w, w3, acc1))));
            acc2 = fmaf(xc.x, w0, fmaf(xc.y, w1, fmaf(xc.z, w2_, fmaf(xc.w, w3, acc2))));
            acc3 = fmaf(xd.x, w0, fmaf(xd.y, w1, fmaf(xd.z, w2_, fmaf(xd.w, w3, acc3))));
        }
        if (r0 + 0 < rows) out[(size_t)(base + r0 + 0) * CC + c] = acc0;
        if (r0 + 1 < rows) out[(size_t)(base + r0 + 1) * CC + c] = acc1;
        if (r0 + 2 < rows) out[(size_t)(base + r0 + 2) * CC + c] = acc2;
        if (r0 + 3 < rows) out[(size_t)(base + r0 + 3) * CC + c] = acc3;
    }
}

extern "C" void kernel_launch(void* const* d_in, const int* in_sizes, int n_in,
                              void* d_out, int out_size, void* d_ws, size_t ws_size,
                              hipStream_t stream) {
    const float* x    = (const float*)d_in[0];
    const int*   ei   = (const int*)d_in[1];
    const float* ea   = (const float*)d_in[2];
    const float* Wn   = (const float*)d_in[3];
    const float* We   = (const float*)d_in[4];
    const float* wt   = (const float*)d_in[5];
    const float* Ws   = (const float*)d_in[6];
    const float* bias = (const float*)d_in[7];
    float* out = (float*)d_out;
    const int N = in_sizes[0] / CC;
    const int E = in_sizes[1] / 2;
    const int nb = (N + 255) / 256;          // scan blocks (<= 256)

    // workspace layout (floats; 16B alignment kept for float4/int2 buffers)
    float* ws = (float*)d_ws;
    size_t o = 0;
    _Float16* xp16 = (_Float16*)(ws + o); o += (size_t)N * HCdim / 2;  // 19.2 MB
    float* sA = ws + o;                  o += (size_t)N * 8;       // 1.6 MB
    float* u  = ws + o;                  o += 128;
    float4* alphaE = (float4*)(ws + o);  o += (size_t)E * 4;       // 12.8 MB
    int2*  perm = (int2*)(ws + o);       o += (size_t)E * 2 + 32;
    _Float16* ea16 = (_Float16*)(ws + o); o += (size_t)E * ECC / 2; // 51.2 MB
    int* deg    = (int*)(ws + o);        o += N;
    int* off    = (int*)(ws + o);        o += N + 1;
    int* cursor = (int*)(ws + o);        o += N;
    int* bsum   = (int*)(ws + o);        o += 256;
    int* boff   = (int*)(ws + o);        o += 256;
    o += (4 - (o & 3)) & 3;              // realign
    float* aggrN = ws + o;               o += (size_t)N * HCdim;   // 38.4 MB
    (void)ws_size; (void)n_in; (void)out_size;

    (void)hipMemsetAsync(deg, 0, (size_t)N * sizeof(int), stream);

    tm_k0<<<1, 96, 0, stream>>>(We, wt, u);
    tm_k1<<<(N + K1_ROWS - 1) / K1_ROWS, 192, 0, stream>>>(x, Wn, wt, ei, deg,
                                                           xp16, sA, N, E);
    tm_scanA<<<nb, 256, 0, stream>>>(deg, bsum, N);
    tm_scanB<<<1, 256, 0, stream>>>(bsum, boff, nb);
    tm_scanC<<<nb, 256, 0, stream>>>(deg, boff, off, cursor, N);
    tm_alpha<<<(E + 255) / 256, 256, 0, stream>>>(ei, ea, u, sA, cursor,
                                                  alphaE, perm, ea16, E);
    tm_agg<<<(N + 7) / 8, 192, 0, stream>>>(perm, off, ea, We,
                                            (const float*)alphaE, xp16, ea16,
                                            aggrN, N);
    tm_k5<<<512, 256, 0, stream>>>(aggrN, Ws, bias, out, N);
}